// Round 3
// baseline (357.659 us; speedup 1.0000x reference)
//
#include <hip/hip_runtime.h>
#include <hip/hip_bf16.h>

#define B 4
#define T 4096
#define D 512
#define KKEEP 1024
#define RSQRT_D 0.044194173824159216f  // 1/sqrt(512)

// ---------------------------------------------------------------------------
// Kernel 1: q_last[b,j] = h[b,T-1,:] @ Wq[:,j] + bq[j]
// grid (B, 2), block 256 — thread j reads Wq column-coalesced across lanes.
__global__ void k_qlast(const float* __restrict__ h, const float* __restrict__ Wq,
                        const float* __restrict__ bq, float* __restrict__ qlast) {
    int b = blockIdx.x;
    int j = blockIdx.y * blockDim.x + threadIdx.x;  // 0..511
    __shared__ float hs[D];
    const float* hrow = h + ((size_t)b * T + (T - 1)) * D;
    for (int i = threadIdx.x; i < D; i += blockDim.x) hs[i] = hrow[i];
    __syncthreads();
    float acc = bq[j];
    for (int d = 0; d < D; ++d) acc += hs[d] * Wq[d * D + j];
    qlast[b * D + j] = acc;
}

// ---------------------------------------------------------------------------
// Kernel 2: wvec[b,d] = Wk[d,:] . qlast[b,:]   (and cvec[b] = bk . qlast[b])
// grid (B, D/4 + 1), block 256 = 4 waves, one wave per row d.
__global__ void k_wk(const float* __restrict__ Wk, const float* __restrict__ bk,
                     const float* __restrict__ qlast,
                     float* __restrict__ wvec, float* __restrict__ cvec) {
    int b = blockIdx.x;
    int lane = threadIdx.x & 63;
    int wave = threadIdx.x >> 6;
    const float* qb = qlast + b * D;
    if (blockIdx.y == D / 4) {
        if (wave == 0) {
            float acc = 0.f;
            for (int k = lane; k < D; k += 64) acc += bk[k] * qb[k];
            for (int off = 32; off; off >>= 1) acc += __shfl_down(acc, off);
            if (lane == 0) cvec[b] = acc;
        }
        return;
    }
    int d = blockIdx.y * 4 + wave;
    const float* row = Wk + (size_t)d * D;
    float acc = 0.f;
    for (int k = lane; k < D; k += 64) acc += row[k] * qb[k];
    for (int off = 32; off; off >>= 1) acc += __shfl_down(acc, off);
    if (lane == 0) wvec[b * D + d] = acc;
}

// ---------------------------------------------------------------------------
// Kernel 3: scores[b,s] = (h[b,s,:] . wvec[b] + cvec[b]) * rsqrt(D)
// grid (B, T/4), block 256 = 4 waves, one wave per row s; float4 loads.
__global__ void k_scores(const float* __restrict__ h, const float* __restrict__ wvec,
                         const float* __restrict__ cvec, float* __restrict__ sc) {
    int b = blockIdx.x;
    __shared__ float ws[D];
    for (int i = threadIdx.x; i < D; i += blockDim.x) ws[i] = wvec[b * D + i];
    __syncthreads();
    int lane = threadIdx.x & 63;
    int wave = threadIdx.x >> 6;
    int s = blockIdx.y * 4 + wave;
    const float4* h4 = (const float4*)(h + ((size_t)b * T + s) * D);
    const float4* w4 = (const float4*)ws;
    float acc = 0.f;
    for (int k = lane; k < D / 4; k += 64) {  // 2 iters
        float4 a = h4[k], w = w4[k];
        acc += a.x * w.x + a.y * w.y + a.z * w.z + a.w * w.w;
    }
    for (int off = 32; off; off >>= 1) acc += __shfl_down(acc, off);
    if (lane == 0) sc[b * T + s] = (acc + cvec[b]) * RSQRT_D;
}

// ---------------------------------------------------------------------------
// Kernel 4: per batch — exact top-1024 (bitonic sort of (ord(val)<<32 | ~idx)),
// softmax over selected, wsum[b,:] = sum attn_s * h[b,s,:].
// grid B, block 1024. LDS: 32KB keys + 12KB scratch.
__global__ __launch_bounds__(1024) void k_topk(const float* __restrict__ h,
                                               const float* __restrict__ sc,
                                               float* __restrict__ wsum) {
    int b = blockIdx.x;
    int tid = threadIdx.x;
    __shared__ unsigned long long keys[T];
    __shared__ float wts[KKEEP];
    __shared__ int sel[KKEEP];
    __shared__ float red[1024];
    __shared__ float mv;

    for (int i = tid; i < T; i += 1024) {
        unsigned u = __float_as_uint(sc[b * T + i]);
        unsigned ord = (u & 0x80000000u) ? ~u : (u | 0x80000000u);  // monotone map
        keys[i] = ((unsigned long long)ord << 32) | (unsigned)(~i); // tie: smaller i wins
    }
    __syncthreads();

    // Bitonic sort ascending over 4096 keys.
    for (int k = 2; k <= T; k <<= 1) {
        for (int j = k >> 1; j > 0; j >>= 1) {
            for (int i = tid; i < T; i += 1024) {
                int ixj = i ^ j;
                if (ixj > i) {
                    unsigned long long a = keys[i], c = keys[ixj];
                    bool up = ((i & k) == 0);
                    if ((a > c) == up) { keys[i] = c; keys[ixj] = a; }
                }
            }
            __syncthreads();
        }
    }

    // Top-KKEEP live at keys[T-KKEEP .. T-1]; decode value + index.
    unsigned long long kk = keys[(T - KKEEP) + tid];
    unsigned hi = (unsigned)(kk >> 32);
    unsigned u = (hi & 0x80000000u) ? (hi ^ 0x80000000u) : ~hi;  // inverse ord
    float val = __uint_as_float(u);
    int idx = (int)(~(unsigned)(kk & 0xFFFFFFFFu));
    if (tid == KKEEP - 1) mv = val;  // global max (ascending sort)
    __syncthreads();

    float e = __expf(val - mv);
    red[tid] = e;
    __syncthreads();
    for (int off = 512; off; off >>= 1) {
        if (tid < off) red[tid] += red[tid + off];
        __syncthreads();
    }
    float inv_denom = 1.0f / red[0];
    __syncthreads();
    wts[tid] = e * inv_denom;
    sel[tid] = idx;
    __syncthreads();

    // wsum[d] = sum_t wts[t] * h[b, sel[t], d]; two halves of the block
    // stride over t, 512 dims each, coalesced 2KB row reads.
    int d = tid & 511, g = tid >> 9;
    float acc = 0.f;
    for (int t = g; t < KKEEP; t += 2)
        acc += wts[t] * h[((size_t)b * T + sel[t]) * D + d];
    red[tid] = acc;
    __syncthreads();
    if (tid < D) wsum[b * D + tid] = red[tid] + red[tid + D];
}

// ---------------------------------------------------------------------------
// Kernel 5: out[b,j] = wsum[b,:] @ Wv[:,j] + bv[j]   (sum attn == 1 folds bv)
__global__ void k_out(const float* __restrict__ wsum, const float* __restrict__ Wv,
                      const float* __restrict__ bv, float* __restrict__ out) {
    int b = blockIdx.x;
    int j = blockIdx.y * blockDim.x + threadIdx.x;
    __shared__ float ws[D];
    for (int i = threadIdx.x; i < D; i += blockDim.x) ws[i] = wsum[b * D + i];
    __syncthreads();
    float acc = bv[j];
    for (int d = 0; d < D; ++d) acc += ws[d] * Wv[d * D + j];
    out[b * D + j] = acc;
}

// ---------------------------------------------------------------------------
extern "C" void kernel_launch(void* const* d_in, const int* in_sizes, int n_in,
                              void* d_out, int out_size, void* d_ws, size_t ws_size,
                              hipStream_t stream) {
    const float* h  = (const float*)d_in[0];
    const float* Wq = (const float*)d_in[1];
    const float* bq = (const float*)d_in[2];
    const float* Wk = (const float*)d_in[3];
    const float* bk = (const float*)d_in[4];
    const float* Wv = (const float*)d_in[5];
    const float* bv = (const float*)d_in[6];
    float* out = (float*)d_out;

    float* ws = (float*)d_ws;
    float* qlast = ws;           // B*D
    float* wvec  = ws + 2048;    // B*D
    float* cvec  = ws + 4096;    // B (padded)
    float* sc    = ws + 4352;    // B*T
    float* wsum  = ws + 4352 + B * T;  // B*D

    k_qlast<<<dim3(B, 2), 256, 0, stream>>>(h, Wq, bq, qlast);
    k_wk<<<dim3(B, D / 4 + 1), 256, 0, stream>>>(Wk, bk, qlast, wvec, cvec);
    k_scores<<<dim3(B, T / 4), 256, 0, stream>>>(h, wvec, cvec, sc);
    k_topk<<<dim3(B), 1024, 0, stream>>>(h, sc, wsum);
    k_out<<<dim3(B, 2), 256, 0, stream>>>(wsum, Wv, bv, out);
}

// Round 4
// 111.378 us; speedup vs baseline: 3.2112x; 3.2112x over previous
//
#include <hip/hip_runtime.h>
#include <hip/hip_bf16.h>

#define B 4
#define T 4096
#define D 512
#define KKEEP 1024
#define RSQRT_D 0.044194173824159216f  // 1/sqrt(512)

// Monotone float->uint map: preserves total order, descending floats = descending uints.
__device__ __forceinline__ unsigned f2ord(float f) {
    unsigned u = __float_as_uint(f);
    return (u & 0x80000000u) ? ~u : (u | 0x80000000u);
}
__device__ __forceinline__ float ord2f(unsigned o) {
    return __uint_as_float((o & 0x80000000u) ? (o ^ 0x80000000u) : ~o);
}

// ---------------------------------------------------------------------------
// Zero-init accumulators (d_ws/d_out are poisoned 0xAA before every timed call).
__global__ void k_zero(float* a, int na, float* o, int no) {
    int i = blockIdx.x * blockDim.x + threadIdx.x;
    if (i < na) a[i] = 0.f;
    if (i < no) o[i] = 0.f;
}

// ---------------------------------------------------------------------------
// Kernel 1: qlast[b,j] += h[b,T-1,d0:d0+64] @ Wq[d0:d0+64, j]  (+bq[j] on z==0)
// grid (B, 2, 8), block 256 — d-loop split across z for 64 blocks of parallelism.
__global__ void k_qlast(const float* __restrict__ h, const float* __restrict__ Wq,
                        const float* __restrict__ bq, float* __restrict__ qlast) {
    int b = blockIdx.x;
    int j = blockIdx.y * 256 + threadIdx.x;
    int d0 = blockIdx.z * 64;
    __shared__ float hs[64];
    const float* hrow = h + ((size_t)b * T + (T - 1)) * D + d0;
    if (threadIdx.x < 64) hs[threadIdx.x] = hrow[threadIdx.x];
    __syncthreads();
    float acc = (blockIdx.z == 0) ? bq[j] : 0.f;
    for (int d = 0; d < 64; ++d) acc += hs[d] * Wq[(size_t)(d0 + d) * D + j];
    atomicAdd(&qlast[b * D + j], acc);
}

// ---------------------------------------------------------------------------
// Kernel 2: wvec[b,d] = Wk[d,:] . qlast[b,:]   (and cvec[b] = bk . qlast[b])
__global__ void k_wk(const float* __restrict__ Wk, const float* __restrict__ bk,
                     const float* __restrict__ qlast,
                     float* __restrict__ wvec, float* __restrict__ cvec) {
    int b = blockIdx.x;
    int lane = threadIdx.x & 63;
    int wave = threadIdx.x >> 6;
    const float* qb = qlast + b * D;
    if (blockIdx.y == D / 4) {
        if (wave == 0) {
            float acc = 0.f;
            for (int k = lane; k < D; k += 64) acc += bk[k] * qb[k];
            for (int off = 32; off; off >>= 1) acc += __shfl_down(acc, off);
            if (lane == 0) cvec[b] = acc;
        }
        return;
    }
    int d = blockIdx.y * 4 + wave;
    const float* row = Wk + (size_t)d * D;
    float acc = 0.f;
    for (int k = lane; k < D; k += 64) acc += row[k] * qb[k];
    for (int off = 32; off; off >>= 1) acc += __shfl_down(acc, off);
    if (lane == 0) wvec[b * D + d] = acc;
}

// ---------------------------------------------------------------------------
// Kernel 3: sc[b,s] = (h[b,s,:] . wvec[b] + cvec[b]) * rsqrt(D)
__global__ void k_scores(const float* __restrict__ h, const float* __restrict__ wvec,
                         const float* __restrict__ cvec, float* __restrict__ sc) {
    int b = blockIdx.x;
    __shared__ float ws[D];
    for (int i = threadIdx.x; i < D; i += blockDim.x) ws[i] = wvec[b * D + i];
    __syncthreads();
    int lane = threadIdx.x & 63;
    int wave = threadIdx.x >> 6;
    int s = blockIdx.y * 4 + wave;
    const float4* h4 = (const float4*)(h + ((size_t)b * T + s) * D);
    const float4* w4 = (const float4*)ws;
    float acc = 0.f;
    for (int k = lane; k < D / 4; k += 64) {
        float4 a = h4[k], w = w4[k];
        acc += a.x * w.x + a.y * w.y + a.z * w.z + a.w * w.w;
    }
    for (int off = 32; off; off >>= 1) acc += __shfl_down(acc, off);
    if (lane == 0) sc[b * T + s] = (acc + cvec[b]) * RSQRT_D;
}

// ---------------------------------------------------------------------------
// Kernel 4: per batch — exact top-1024 via 4-pass 8-bit radix select on ord keys,
// ties broken by smallest index; emit normalized (idx, weight) list.
__global__ __launch_bounds__(1024) void k_select(const float* __restrict__ sc,
                                                 unsigned* __restrict__ selI,
                                                 float* __restrict__ selW) {
    int b = blockIdx.x;
    int tid = threadIdx.x;
    __shared__ unsigned ordk[T];     // 16KB
    __shared__ int hist[256];        // 1KB
    __shared__ float red[16];
    __shared__ unsigned sI[KKEEP];   // 4KB
    __shared__ float sW[KKEEP];      // 4KB
    __shared__ unsigned tieI[T];     // 16KB (worst case)
    __shared__ unsigned sh_pv;
    __shared__ int sh_r, sh_cnt, sh_tiecnt;
    __shared__ float sh_max, sh_inv;

    // Stage keys + block max.
    float sv[4];
    float lmax = -INFINITY;
#pragma unroll
    for (int k = 0; k < 4; ++k) {
        int i = tid + k * 1024;
        float v = sc[b * T + i];
        sv[k] = v;
        ordk[i] = f2ord(v);
        lmax = fmaxf(lmax, v);
    }
    for (int off = 32; off; off >>= 1) lmax = fmaxf(lmax, __shfl_down(lmax, off));
    if ((tid & 63) == 0) red[tid >> 6] = lmax;
    __syncthreads();
    if (tid == 0) {
        float m = red[0];
        for (int w = 1; w < 16; ++w) m = fmaxf(m, red[w]);
        sh_max = m; sh_pv = 0; sh_r = KKEEP; sh_cnt = 0; sh_tiecnt = 0;
    }
    __syncthreads();

    // Radix select: find v* = KKEEP-th largest key, r = #ties-to-include.
    for (int p = 24; p >= 0; p -= 8) {
        if (tid < 256) hist[tid] = 0;
        __syncthreads();
        unsigned pv = sh_pv;
#pragma unroll
        for (int k = 0; k < 4; ++k) {
            unsigned key = ordk[tid + k * 1024];
            bool act = (p == 24) || ((key >> (p + 8)) == pv);
            if (act) atomicAdd(&hist[(key >> p) & 255], 1);
        }
        __syncthreads();
        if (tid < 64) {  // wave 0: suffix-scan 256 bins, pick digit containing rank r
            int r = sh_r;
            int c0 = hist[tid * 4], c1 = hist[tid * 4 + 1];
            int c2 = hist[tid * 4 + 2], c3 = hist[tid * 4 + 3];
            int s = c0 + c1 + c2 + c3;
            int cum = s;
            for (int off = 1; off < 64; off <<= 1) {
                int v = __shfl_down(cum, off);
                if (tid + off < 64) cum += v;
            }
            int base = cum - s;  // count of keys with digit >= 4*(tid+1)
            if (base < r && r <= cum) {  // exactly one lane
                int d, sg;
                if (r <= base + c3)                { d = 3; sg = base; }
                else if (r <= base + c3 + c2)      { d = 2; sg = base + c3; }
                else if (r <= base + c3 + c2 + c1) { d = 1; sg = base + c3 + c2; }
                else                               { d = 0; sg = base + c3 + c2 + c1; }
                sh_pv = (pv << 8) | (unsigned)(tid * 4 + d);
                sh_r = r - sg;
            }
        }
        __syncthreads();
    }

    unsigned vstar = sh_pv;
    int rtie = sh_r;
    float gmax = sh_max;

    // Append strictly-greater; collect ties.
#pragma unroll
    for (int k = 0; k < 4; ++k) {
        int i = tid + k * 1024;
        unsigned key = ordk[i];
        if (key > vstar) {
            int pos = atomicAdd(&sh_cnt, 1);
            sI[pos] = (unsigned)i;
            sW[pos] = __expf(sv[k] - gmax);
        } else if (key == vstar) {
            int pos = atomicAdd(&sh_tiecnt, 1);
            tieI[pos] = (unsigned)i;
        }
    }
    __syncthreads();

    // Include the rtie smallest-index ties (usually rtie == tiecnt == 1).
    int tcnt = sh_tiecnt;
    float tw = __expf(ord2f(vstar) - gmax);
    for (int t = tid; t < tcnt; t += 1024) {
        unsigned my = tieI[t];
        int rank = 0;
        for (int o = 0; o < tcnt; ++o) rank += (tieI[o] < my);
        if (rank < rtie) {
            int pos = atomicAdd(&sh_cnt, 1);
            sI[pos] = my;
            sW[pos] = tw;
        }
    }
    __syncthreads();

    // Softmax denominator over the 1024 selected; normalize; write out.
    float lsum = sW[tid];
    for (int off = 32; off; off >>= 1) lsum += __shfl_down(lsum, off);
    if ((tid & 63) == 0) red[tid >> 6] = lsum;
    __syncthreads();
    if (tid == 0) {
        float s = 0.f;
        for (int w = 0; w < 16; ++w) s += red[w];
        sh_inv = 1.0f / s;
    }
    __syncthreads();
    selI[b * KKEEP + tid] = sI[tid];
    selW[b * KKEEP + tid] = sW[tid] * sh_inv;
}

// ---------------------------------------------------------------------------
// Kernel 5: wsum[b,:] += sum over 32 selected rows of w * h[b,idx,:]
// grid (B, 32), block 512 = 4 groups x 128 threads; float4 gathers (h is L3-hot).
__global__ __launch_bounds__(512) void k_wsum(const float* __restrict__ h,
                                              const unsigned* __restrict__ selI,
                                              const float* __restrict__ selW,
                                              float* __restrict__ wsum) {
    int b = blockIdx.x;
    int e0 = blockIdx.y * 32;
    int tid = threadIdx.x;
    int g = tid >> 7, l = tid & 127;
    __shared__ float4 red4[512];
    float4 acc = make_float4(0.f, 0.f, 0.f, 0.f);
    for (int e = g; e < 32; e += 4) {
        unsigned s = selI[b * KKEEP + e0 + e];
        float w = selW[b * KKEEP + e0 + e];
        float4 v = ((const float4*)(h + ((size_t)b * T + s) * D))[l];
        acc.x += w * v.x; acc.y += w * v.y; acc.z += w * v.z; acc.w += w * v.w;
    }
    red4[tid] = acc;
    __syncthreads();
    if (tid < 128) {
        float4 a = red4[tid], b1 = red4[tid + 128], c = red4[tid + 256], d4 = red4[tid + 384];
        float* wd = &wsum[b * D + tid * 4];
        atomicAdd(wd + 0, a.x + b1.x + c.x + d4.x);
        atomicAdd(wd + 1, a.y + b1.y + c.y + d4.y);
        atomicAdd(wd + 2, a.z + b1.z + c.z + d4.z);
        atomicAdd(wd + 3, a.w + b1.w + c.w + d4.w);
    }
}

// ---------------------------------------------------------------------------
// Kernel 6: out[b,j] += wsum[b,d0:d0+64] @ Wv[d0:d0+64, j]  (+bv[j] on z==0)
__global__ void k_out(const float* __restrict__ wsum, const float* __restrict__ Wv,
                      const float* __restrict__ bv, float* __restrict__ out) {
    int b = blockIdx.x;
    int j = blockIdx.y * 256 + threadIdx.x;
    int d0 = blockIdx.z * 64;
    __shared__ float ws_[64];
    if (threadIdx.x < 64) ws_[threadIdx.x] = wsum[b * D + d0 + threadIdx.x];
    __syncthreads();
    float acc = (blockIdx.z == 0) ? bv[j] : 0.f;
    for (int d = 0; d < 64; ++d) acc += ws_[d] * Wv[(size_t)(d0 + d) * D + j];
    atomicAdd(&out[b * D + j], acc);
}

// ---------------------------------------------------------------------------
extern "C" void kernel_launch(void* const* d_in, const int* in_sizes, int n_in,
                              void* d_out, int out_size, void* d_ws, size_t ws_size,
                              hipStream_t stream) {
    const float* h  = (const float*)d_in[0];
    const float* Wq = (const float*)d_in[1];
    const float* bq = (const float*)d_in[2];
    const float* Wk = (const float*)d_in[3];
    const float* bk = (const float*)d_in[4];
    const float* Wv = (const float*)d_in[5];
    const float* bv = (const float*)d_in[6];
    float* out = (float*)d_out;

    float* ws = (float*)d_ws;
    float* qlast   = ws;                       // B*D = 2048, zero-init (atomics)
    float* wsum    = ws + 2048;                // B*D = 2048, zero-init (atomics)
    float* wvec    = ws + 4096;                // B*D
    float* cvec    = ws + 6144;                // B (padded to 256)
    float* sc      = ws + 6400;                // B*T = 16384
    unsigned* selI = (unsigned*)(ws + 22784);  // B*KKEEP = 4096
    float* selW    = ws + 26880;               // B*KKEEP = 4096

    k_zero<<<dim3(8), 512, 0, stream>>>(qlast, 4096, out, out_size);  // qlast+wsum contiguous
    k_qlast<<<dim3(B, 2, 8), 256, 0, stream>>>(h, Wq, bq, qlast);
    k_wk<<<dim3(B, D / 4 + 1), 256, 0, stream>>>(Wk, bk, qlast, wvec, cvec);
    k_scores<<<dim3(B, T / 4), 256, 0, stream>>>(h, wvec, cvec, sc);
    k_select<<<dim3(B), 1024, 0, stream>>>(sc, selI, selW);
    k_wsum<<<dim3(B, 32), 512, 0, stream>>>(h, selI, selW, wsum);
    k_out<<<dim3(B, 2, 8), 256, 0, stream>>>(wsum, Wv, bv, out);
}